// Round 2
// baseline (2597.839 us; speedup 1.0000x reference)
//
#include <hip/hip_runtime.h>

#define E  4096
#define NN 16384
#define HH 256
#define WL_CAP 2048
#define MARGIN 0.25f

// ---------------------------------------------------------------------------
// init: zero the refine-worklist counter (ws is poisoned 0xAA every call)
// ---------------------------------------------------------------------------
__global__ void init_kernel(int* cnt) { if (threadIdx.x == 0) *cnt = 0; }

// ---------------------------------------------------------------------------
// Kernel 1: K64[h,e] = sum_k X[hub[h],k] * Wk[e,k] + bk[e]   (fp64 accum)
// fp32 inputs -> fp64 products are EXACT; accumulation error ~1e-13 rel.
// BM=64 x BN=64 x BK=16, 256 threads, 4x4 fp64 microtile. grid (64,4).
// ---------------------------------------------------------------------------
__global__ __launch_bounds__(256) void k_proj64_kernel(
    const float* __restrict__ X, const int* __restrict__ hub,
    const float* __restrict__ Wk, const float* __restrict__ bk,
    double* __restrict__ K64)
{
    __shared__ double As[16][68];
    __shared__ double Bs[16][68];
    __shared__ int rows[64];

    const int t  = threadIdx.x;
    const int m0 = blockIdx.y * 64;   // hub rows
    const int n0 = blockIdx.x * 64;   // e cols

    if (t < 64) rows[t] = hub[m0 + t];
    __syncthreads();

    const int tx = t & 15, ty = t >> 4;
    const int kI = (t & 3) * 4, rr = t >> 2;   // rr 0..63

    double acc[4][4] = {};

    for (int k0 = 0; k0 < E; k0 += 16) {
        const float4 a4 = *(const float4*)&X[(size_t)rows[rr] * E + k0 + kI];
        As[kI + 0][rr] = (double)a4.x; As[kI + 1][rr] = (double)a4.y;
        As[kI + 2][rr] = (double)a4.z; As[kI + 3][rr] = (double)a4.w;
        const float4 b4 = *(const float4*)&Wk[(size_t)(n0 + rr) * E + k0 + kI];
        Bs[kI + 0][rr] = (double)b4.x; Bs[kI + 1][rr] = (double)b4.y;
        Bs[kI + 2][rr] = (double)b4.z; Bs[kI + 3][rr] = (double)b4.w;
        __syncthreads();
#pragma unroll
        for (int k = 0; k < 16; ++k) {
            double av[4], bv[4];
#pragma unroll
            for (int i = 0; i < 4; ++i) av[i] = As[k][ty * 4 + i];
#pragma unroll
            for (int j = 0; j < 4; ++j) bv[j] = Bs[k][tx * 4 + j];
#pragma unroll
            for (int i = 0; i < 4; ++i)
#pragma unroll
                for (int j = 0; j < 4; ++j)
                    acc[i][j] = fma(av[i], bv[j], acc[i][j]);
        }
        __syncthreads();
    }

#pragma unroll
    for (int i = 0; i < 4; ++i)
#pragma unroll
        for (int j = 0; j < 4; ++j)
            K64[(size_t)(m0 + ty * 4 + i) * E + n0 + tx * 4 + j] =
                acc[i][j] + (double)bk[n0 + tx * 4 + j];
}

// ---------------------------------------------------------------------------
// Kernel 2: S = K64 @ Wq (fp64). Outputs:
//   S64T[e'][h]  (transposed, for coalesced refine reads)
//   S32[h][e']   (fp32 rounding of the near-exact S — best possible fp32 S)
// Same tiling as kernel 1 (A.B form). grid (64,4).
// ---------------------------------------------------------------------------
__global__ __launch_bounds__(256) void s_proj64_kernel(
    const double* __restrict__ K64, const float* __restrict__ Wq,
    double* __restrict__ S64T, float* __restrict__ S32)
{
    __shared__ double As[16][68];
    __shared__ double Bs[16][68];

    const int t  = threadIdx.x;
    const int m0 = blockIdx.y * 64;   // h rows
    const int n0 = blockIdx.x * 64;   // e' cols

    const int tx = t & 15, ty = t >> 4;
    const int kI = (t & 3) * 4, rr = t >> 2;   // A staging
    const int kk = t >> 4, bn = (t & 15) * 4;  // B staging

    double acc[4][4] = {};

    for (int k0 = 0; k0 < E; k0 += 16) {
        const double2 a0 = *(const double2*)&K64[(size_t)(m0 + rr) * E + k0 + kI];
        const double2 a1 = *(const double2*)&K64[(size_t)(m0 + rr) * E + k0 + kI + 2];
        As[kI + 0][rr] = a0.x; As[kI + 1][rr] = a0.y;
        As[kI + 2][rr] = a1.x; As[kI + 3][rr] = a1.y;
        const float4 b4 = *(const float4*)&Wq[(size_t)(k0 + kk) * E + n0 + bn];
        Bs[kk][bn + 0] = (double)b4.x; Bs[kk][bn + 1] = (double)b4.y;
        Bs[kk][bn + 2] = (double)b4.z; Bs[kk][bn + 3] = (double)b4.w;
        __syncthreads();
#pragma unroll
        for (int k = 0; k < 16; ++k) {
            double av[4], bv[4];
#pragma unroll
            for (int i = 0; i < 4; ++i) av[i] = As[k][ty * 4 + i];
#pragma unroll
            for (int j = 0; j < 4; ++j) bv[j] = Bs[k][tx * 4 + j];
#pragma unroll
            for (int i = 0; i < 4; ++i)
#pragma unroll
                for (int j = 0; j < 4; ++j)
                    acc[i][j] = fma(av[i], bv[j], acc[i][j]);
        }
        __syncthreads();
    }

#pragma unroll
    for (int i = 0; i < 4; ++i) {
        const int h = m0 + ty * 4 + i;
        float4 r;
        float* rp = &r.x;
#pragma unroll
        for (int j = 0; j < 4; ++j) {
            const int ec = n0 + tx * 4 + j;
            S64T[(size_t)ec * HH + h] = acc[i][j];
            rp[j] = (float)acc[i][j];
        }
        *(float4*)&S32[(size_t)h * E + n0 + tx * 4] = r;
    }
}

// ---------------------------------------------------------------------------
// Kernel 2b: c64[h] = dot(bq, K64[h,:]) in fp64 (+ fp32 copy for fast path)
// ---------------------------------------------------------------------------
__global__ __launch_bounds__(256) void cvec64_kernel(
    const float* __restrict__ bq, const double* __restrict__ K64,
    double* __restrict__ c64, float* __restrict__ c32)
{
    const int h = blockIdx.x;
    const int t = threadIdx.x;
    double s = 0.0;
    for (int e = t; e < E; e += 256)
        s = fma((double)bq[e], K64[(size_t)h * E + e], s);
#pragma unroll
    for (int m = 32; m; m >>= 1) s += __shfl_down(s, m, 64);
    __shared__ double red[4];
    if ((t & 63) == 0) red[t >> 6] = s;
    __syncthreads();
    if (t == 0) {
        const double v = red[0] + red[1] + red[2] + red[3];
        c64[h] = v; c32[h] = (float)v;
    }
}

// ---------------------------------------------------------------------------
// Kernel 3: fast fp32 scores + top-2 argmax. Nodes whose (top1-top2) gap is
// below MARGIN go to the refine worklist (expected ~120 of 16384).
// Per block: 32 nodes x 256 hubs, BK=32, 4x8 microtile. grid 512.
// ---------------------------------------------------------------------------
__global__ __launch_bounds__(256) void scores_argmax_kernel(
    const float* __restrict__ X, const float* __restrict__ S,
    const float* __restrict__ craw, const int* __restrict__ hub,
    int* __restrict__ out, int* __restrict__ cnt, int* __restrict__ wl)
{
    __shared__ float As[32][36];    // As[k][m], 32 nodes
    __shared__ float Bs[32][264];   // Bs[k][swizzled h], 256 hubs

    const int t    = threadIdx.x;
    const int m0   = blockIdx.x * 32;
    const int tx   = t & 31;        // hub group: hubs tx*8 .. tx*8+7
    const int ty   = t >> 5;        // node group: nodes ty*4 .. ty*4+3
    const int kIdx = (t & 7) * 4;
    const int arow = t >> 3;        // 0..31
    const int swz  = 8 * (t & 3);   // staging swizzle = 8*((k>>2)&3)

    float acc[4][8] = {};

    for (int k0 = 0; k0 < E; k0 += 32) {
        {
            const float4 a4 = *(const float4*)&X[(size_t)(m0 + arow) * E + k0 + kIdx];
            As[kIdx + 0][arow] = a4.x; As[kIdx + 1][arow] = a4.y;
            As[kIdx + 2][arow] = a4.z; As[kIdx + 3][arow] = a4.w;
        }
#pragma unroll
        for (int it = 0; it < 8; ++it) {
            const int h = it * 32 + arow;
            const float4 b4 = *(const float4*)&S[(size_t)h * E + k0 + kIdx];
            const int c = h ^ swz;
            Bs[kIdx + 0][c] = b4.x; Bs[kIdx + 1][c] = b4.y;
            Bs[kIdx + 2][c] = b4.z; Bs[kIdx + 3][c] = b4.w;
        }
        __syncthreads();
#pragma unroll
        for (int k = 0; k < 32; ++k) {
            const float4 a = *(const float4*)&As[k][ty * 4];
            const int s = (k >> 2) & 3;
            const float* bp = &Bs[k][8 * (tx ^ s)];
            const float4 b0 = *(const float4*)bp;
            const float4 b1 = *(const float4*)(bp + 4);
            const float av[4] = {a.x, a.y, a.z, a.w};
            const float bv[8] = {b0.x, b0.y, b0.z, b0.w, b1.x, b1.y, b1.z, b1.w};
#pragma unroll
            for (int i = 0; i < 4; ++i)
#pragma unroll
                for (int j = 0; j < 8; ++j)
                    acc[i][j] += av[i] * bv[j];
        }
        __syncthreads();
    }

    float cr[8];
#pragma unroll
    for (int j = 0; j < 8; ++j) cr[j] = craw[tx * 8 + j];

#pragma unroll
    for (int i = 0; i < 4; ++i) {
        float v1 = -3.4e38f, v2 = -3.4e38f;
        int   i1 = 0;
#pragma unroll
        for (int j = 0; j < 8; ++j) {
            const float v = acc[i][j] + cr[j];
            if (v > v1)      { v2 = v1; v1 = v; i1 = tx * 8 + j; }
            else if (v > v2) { v2 = v; }
        }
        // butterfly over the 32 tx-lanes (masks <32 stay inside the group)
#pragma unroll
        for (int m = 16; m; m >>= 1) {
            const float ov1 = __shfl_xor(v1, m, 64);
            const int   oi1 = __shfl_xor(i1, m, 64);
            const float ov2 = __shfl_xor(v2, m, 64);
            if (ov1 > v1 || (ov1 == v1 && oi1 < i1)) {
                v2 = fmaxf(v1, ov2); v1 = ov1; i1 = oi1;
            } else {
                v2 = fmaxf(v2, ov1);
            }
        }
        if (tx == 0) {
            const int node = m0 + ty * 4 + i;
            out[node] = hub[i1];
            if (v1 - v2 < MARGIN) {
                const int idx = atomicAdd(cnt, 1);
                if (idx < WL_CAP) wl[idx] = node;
            }
        }
    }
}

// ---------------------------------------------------------------------------
// Kernel 4: fp64 refine of near-tie nodes. Block handles 8 worklist entries;
// thread t owns hub t: score = sum_e X[n,e]*S64T[e,t] + c64[t].
// First-max argmax (tie -> lower hub position) matches np.argmax exactly.
// grid WL_CAP/8 = 256 (idle blocks exit immediately).
// ---------------------------------------------------------------------------
__global__ __launch_bounds__(256) void refine_kernel(
    const float* __restrict__ X, const double* __restrict__ S64T,
    const double* __restrict__ c64, const int* __restrict__ hub,
    const int* __restrict__ cnt, const int* __restrict__ wl,
    int* __restrict__ out)
{
    const int base = blockIdx.x * 8;
    const int n = min(*cnt, WL_CAP);
    if (base >= n) return;

    const int t = threadIdx.x;
    __shared__ int nodes_s[8];
    if (t < 8) nodes_s[t] = wl[(base + t < n) ? (base + t) : base];
    __syncthreads();

    int nd[8];
#pragma unroll
    for (int j = 0; j < 8; ++j) nd[j] = nodes_s[j];

    double acc[8] = {0, 0, 0, 0, 0, 0, 0, 0};
    for (int e = 0; e < E; ++e) {
        const double s = S64T[(size_t)e * HH + t];
#pragma unroll
        for (int j = 0; j < 8; ++j)
            acc[j] = fma((double)X[(size_t)nd[j] * E + e], s, acc[j]);
    }

    __shared__ double rv[256];
    __shared__ int    ri[256];
    for (int j = 0; j < 8; ++j) {
        rv[t] = acc[j] + c64[t];
        ri[t] = t;
        __syncthreads();
        for (int s = 128; s; s >>= 1) {
            if (t < s) {
                const bool better = rv[t + s] > rv[t] ||
                                    (rv[t + s] == rv[t] && ri[t + s] < ri[t]);
                if (better) { rv[t] = rv[t + s]; ri[t] = ri[t + s]; }
            }
            __syncthreads();
        }
        if (t == 0) out[nd[j]] = hub[ri[0]];
        __syncthreads();
    }
}

// ---------------------------------------------------------------------------
// Kernel 5: hub nodes map to themselves (isin override). Must run LAST.
// ---------------------------------------------------------------------------
__global__ void hub_override_kernel(const int* __restrict__ hub,
                                    int* __restrict__ out)
{
    const int t = threadIdx.x;
    if (t < HH) { const int h = hub[t]; out[h] = h; }
}

extern "C" void kernel_launch(void* const* d_in, const int* in_sizes, int n_in,
                              void* d_out, int out_size, void* d_ws, size_t ws_size,
                              hipStream_t stream) {
    const float* X   = (const float*)d_in[0];   // [NN, E]
    const int*   hub = (const int*)  d_in[1];   // [HH]
    const float* Wq  = (const float*)d_in[2];   // [E, E]
    const float* bq  = (const float*)d_in[3];   // [E]
    const float* Wk  = (const float*)d_in[4];   // [E, E]
    const float* bk  = (const float*)d_in[5];   // [E]
    int* out = (int*)d_out;                     // [NN]

    // workspace layout (doubles first for alignment): ~21 MB
    double* K64  = (double*)d_ws;                       // [HH][E]   8 MB
    double* S64T = K64 + (size_t)HH * E;                // [E][HH]   8 MB
    double* c64  = S64T + (size_t)E * HH;               // [HH]      2 KB
    float*  S32  = (float*)(c64 + HH);                  // [HH][E]   4 MB
    float*  c32  = S32 + (size_t)HH * E;                // [HH]      1 KB
    int*    cnt  = (int*)(c32 + HH);                    // [1]
    int*    wl   = cnt + 1;                             // [WL_CAP]  8 KB

    init_kernel<<<dim3(1), 64, 0, stream>>>(cnt);
    k_proj64_kernel<<<dim3(E / 64, HH / 64), 256, 0, stream>>>(X, hub, Wk, bk, K64);
    s_proj64_kernel<<<dim3(E / 64, HH / 64), 256, 0, stream>>>(K64, Wq, S64T, S32);
    cvec64_kernel<<<dim3(HH), 256, 0, stream>>>(bq, K64, c64, c32);
    scores_argmax_kernel<<<dim3(NN / 32), 256, 0, stream>>>(X, S32, c32, hub, out, cnt, wl);
    refine_kernel<<<dim3(WL_CAP / 8), 256, 0, stream>>>(X, S64T, c64, hub, cnt, wl, out);
    hub_override_kernel<<<dim3(1), 256, 0, stream>>>(hub, out);
}

// Round 3
// 1725.307 us; speedup vs baseline: 1.5057x; 1.5057x over previous
//
#include <hip/hip_runtime.h>

#define E  4096
#define NN 16384
#define HH 256
#define WL_CAP 2048
#define REF_SLOTS 512
#define MARGIN 0.0625f

// ---------------------------------------------------------------------------
// init: zero the refine-worklist counter (ws is poisoned 0xAA every call)
// ---------------------------------------------------------------------------
__global__ void init_kernel(int* cnt) { if (threadIdx.x == 0) *cnt = 0; }

// ---------------------------------------------------------------------------
// Kernel 1: K64[h,e] = sum_k X[hub[h],k] * Wk[e,k] + bk[e]   (fp64 accum)
// fp32 inputs -> fp64 products are EXACT; accumulation error ~1e-13 rel.
// BM=64 x BN=64 x BK=16, 256 threads, 4x4 fp64 microtile. grid (64,4).
// ---------------------------------------------------------------------------
__global__ __launch_bounds__(256) void k_proj64_kernel(
    const float* __restrict__ X, const int* __restrict__ hub,
    const float* __restrict__ Wk, const float* __restrict__ bk,
    double* __restrict__ K64)
{
    __shared__ double As[16][68];
    __shared__ double Bs[16][68];
    __shared__ int rows[64];

    const int t  = threadIdx.x;
    const int m0 = blockIdx.y * 64;   // hub rows
    const int n0 = blockIdx.x * 64;   // e cols

    if (t < 64) rows[t] = hub[m0 + t];
    __syncthreads();

    const int tx = t & 15, ty = t >> 4;
    const int kI = (t & 3) * 4, rr = t >> 2;   // rr 0..63

    double acc[4][4] = {};

    for (int k0 = 0; k0 < E; k0 += 16) {
        const float4 a4 = *(const float4*)&X[(size_t)rows[rr] * E + k0 + kI];
        As[kI + 0][rr] = (double)a4.x; As[kI + 1][rr] = (double)a4.y;
        As[kI + 2][rr] = (double)a4.z; As[kI + 3][rr] = (double)a4.w;
        const float4 b4 = *(const float4*)&Wk[(size_t)(n0 + rr) * E + k0 + kI];
        Bs[kI + 0][rr] = (double)b4.x; Bs[kI + 1][rr] = (double)b4.y;
        Bs[kI + 2][rr] = (double)b4.z; Bs[kI + 3][rr] = (double)b4.w;
        __syncthreads();
#pragma unroll
        for (int k = 0; k < 16; ++k) {
            double av[4], bv[4];
#pragma unroll
            for (int i = 0; i < 4; ++i) av[i] = As[k][ty * 4 + i];
#pragma unroll
            for (int j = 0; j < 4; ++j) bv[j] = Bs[k][tx * 4 + j];
#pragma unroll
            for (int i = 0; i < 4; ++i)
#pragma unroll
                for (int j = 0; j < 4; ++j)
                    acc[i][j] = fma(av[i], bv[j], acc[i][j]);
        }
        __syncthreads();
    }

#pragma unroll
    for (int i = 0; i < 4; ++i)
#pragma unroll
        for (int j = 0; j < 4; ++j)
            K64[(size_t)(m0 + ty * 4 + i) * E + n0 + tx * 4 + j] =
                acc[i][j] + (double)bk[n0 + tx * 4 + j];
}

// ---------------------------------------------------------------------------
// Kernel 2: S = K64 @ Wq (fp64). Outputs:
//   S64T[e'][h]  (transposed, for coalesced refine reads)
//   S32[h][e']   (fp32 rounding of the near-exact S — best possible fp32 S)
// Same tiling as kernel 1 (A.B form). grid (64,4).
// ---------------------------------------------------------------------------
__global__ __launch_bounds__(256) void s_proj64_kernel(
    const double* __restrict__ K64, const float* __restrict__ Wq,
    double* __restrict__ S64T, float* __restrict__ S32)
{
    __shared__ double As[16][68];
    __shared__ double Bs[16][68];

    const int t  = threadIdx.x;
    const int m0 = blockIdx.y * 64;   // h rows
    const int n0 = blockIdx.x * 64;   // e' cols

    const int tx = t & 15, ty = t >> 4;
    const int kI = (t & 3) * 4, rr = t >> 2;   // A staging
    const int kk = t >> 4, bn = (t & 15) * 4;  // B staging

    double acc[4][4] = {};

    for (int k0 = 0; k0 < E; k0 += 16) {
        const double2 a0 = *(const double2*)&K64[(size_t)(m0 + rr) * E + k0 + kI];
        const double2 a1 = *(const double2*)&K64[(size_t)(m0 + rr) * E + k0 + kI + 2];
        As[kI + 0][rr] = a0.x; As[kI + 1][rr] = a0.y;
        As[kI + 2][rr] = a1.x; As[kI + 3][rr] = a1.y;
        const float4 b4 = *(const float4*)&Wq[(size_t)(k0 + kk) * E + n0 + bn];
        Bs[kk][bn + 0] = (double)b4.x; Bs[kk][bn + 1] = (double)b4.y;
        Bs[kk][bn + 2] = (double)b4.z; Bs[kk][bn + 3] = (double)b4.w;
        __syncthreads();
#pragma unroll
        for (int k = 0; k < 16; ++k) {
            double av[4], bv[4];
#pragma unroll
            for (int i = 0; i < 4; ++i) av[i] = As[k][ty * 4 + i];
#pragma unroll
            for (int j = 0; j < 4; ++j) bv[j] = Bs[k][tx * 4 + j];
#pragma unroll
            for (int i = 0; i < 4; ++i)
#pragma unroll
                for (int j = 0; j < 4; ++j)
                    acc[i][j] = fma(av[i], bv[j], acc[i][j]);
        }
        __syncthreads();
    }

#pragma unroll
    for (int i = 0; i < 4; ++i) {
        const int h = m0 + ty * 4 + i;
        float4 r;
        float* rp = &r.x;
#pragma unroll
        for (int j = 0; j < 4; ++j) {
            const int ec = n0 + tx * 4 + j;
            S64T[(size_t)ec * HH + h] = acc[i][j];
            rp[j] = (float)acc[i][j];
        }
        *(float4*)&S32[(size_t)h * E + n0 + tx * 4] = r;
    }
}

// ---------------------------------------------------------------------------
// Kernel 2b: c64[h] = dot(bq, K64[h,:]) in fp64 (+ fp32 copy for fast path)
// ---------------------------------------------------------------------------
__global__ __launch_bounds__(256) void cvec64_kernel(
    const float* __restrict__ bq, const double* __restrict__ K64,
    double* __restrict__ c64, float* __restrict__ c32)
{
    const int h = blockIdx.x;
    const int t = threadIdx.x;
    double s = 0.0;
    for (int e = t; e < E; e += 256)
        s = fma((double)bq[e], K64[(size_t)h * E + e], s);
#pragma unroll
    for (int m = 32; m; m >>= 1) s += __shfl_down(s, m, 64);
    __shared__ double red[4];
    if ((t & 63) == 0) red[t >> 6] = s;
    __syncthreads();
    if (t == 0) {
        const double v = red[0] + red[1] + red[2] + red[3];
        c64[h] = v; c32[h] = (float)v;
    }
}

// ---------------------------------------------------------------------------
// Kernel 3: fast fp32 scores + top-2 argmax. Nodes whose (top1-top2) gap is
// below MARGIN go to the refine worklist (expected ~30 of 16384).
// Per block: 32 nodes x 256 hubs, BK=32, 4x8 microtile. grid 512.
// ---------------------------------------------------------------------------
__global__ __launch_bounds__(256) void scores_argmax_kernel(
    const float* __restrict__ X, const float* __restrict__ S,
    const float* __restrict__ craw, const int* __restrict__ hub,
    int* __restrict__ out, int* __restrict__ cnt, int* __restrict__ wl)
{
    __shared__ float As[32][36];    // As[k][m], 32 nodes
    __shared__ float Bs[32][264];   // Bs[k][swizzled h], 256 hubs

    const int t    = threadIdx.x;
    const int m0   = blockIdx.x * 32;
    const int tx   = t & 31;        // hub group: hubs tx*8 .. tx*8+7
    const int ty   = t >> 5;        // node group: nodes ty*4 .. ty*4+3
    const int kIdx = (t & 7) * 4;
    const int arow = t >> 3;        // 0..31
    const int swz  = 8 * (t & 3);   // staging swizzle = 8*((k>>2)&3)

    float acc[4][8] = {};

    for (int k0 = 0; k0 < E; k0 += 32) {
        {
            const float4 a4 = *(const float4*)&X[(size_t)(m0 + arow) * E + k0 + kIdx];
            As[kIdx + 0][arow] = a4.x; As[kIdx + 1][arow] = a4.y;
            As[kIdx + 2][arow] = a4.z; As[kIdx + 3][arow] = a4.w;
        }
#pragma unroll
        for (int it = 0; it < 8; ++it) {
            const int h = it * 32 + arow;
            const float4 b4 = *(const float4*)&S[(size_t)h * E + k0 + kIdx];
            const int c = h ^ swz;
            Bs[kIdx + 0][c] = b4.x; Bs[kIdx + 1][c] = b4.y;
            Bs[kIdx + 2][c] = b4.z; Bs[kIdx + 3][c] = b4.w;
        }
        __syncthreads();
#pragma unroll
        for (int k = 0; k < 32; ++k) {
            const float4 a = *(const float4*)&As[k][ty * 4];
            const int s = (k >> 2) & 3;
            const float* bp = &Bs[k][8 * (tx ^ s)];
            const float4 b0 = *(const float4*)bp;
            const float4 b1 = *(const float4*)(bp + 4);
            const float av[4] = {a.x, a.y, a.z, a.w};
            const float bv[8] = {b0.x, b0.y, b0.z, b0.w, b1.x, b1.y, b1.z, b1.w};
#pragma unroll
            for (int i = 0; i < 4; ++i)
#pragma unroll
                for (int j = 0; j < 8; ++j)
                    acc[i][j] += av[i] * bv[j];
        }
        __syncthreads();
    }

    float cr[8];
#pragma unroll
    for (int j = 0; j < 8; ++j) cr[j] = craw[tx * 8 + j];

#pragma unroll
    for (int i = 0; i < 4; ++i) {
        float v1 = -3.4e38f, v2 = -3.4e38f;
        int   i1 = 0;
#pragma unroll
        for (int j = 0; j < 8; ++j) {
            const float v = acc[i][j] + cr[j];
            if (v > v1)      { v2 = v1; v1 = v; i1 = tx * 8 + j; }
            else if (v > v2) { v2 = v; }
        }
        // butterfly over the 32 tx-lanes (masks <32 stay inside the group)
#pragma unroll
        for (int m = 16; m; m >>= 1) {
            const float ov1 = __shfl_xor(v1, m, 64);
            const int   oi1 = __shfl_xor(i1, m, 64);
            const float ov2 = __shfl_xor(v2, m, 64);
            if (ov1 > v1 || (ov1 == v1 && oi1 < i1)) {
                v2 = fmaxf(v1, ov2); v1 = ov1; i1 = oi1;
            } else {
                v2 = fmaxf(v2, ov1);
            }
        }
        if (tx == 0) {
            const int node = m0 + ty * 4 + i;
            out[node] = hub[i1];
            if (v1 - v2 < MARGIN) {
                const int idx = atomicAdd(cnt, 1);
                if (idx < WL_CAP) wl[idx] = node;
            }
        }
    }
}

// ---------------------------------------------------------------------------
// Kernel 4a: parallel fp64 refine, stage A (partial dot products).
// grid (8 e-chunks, REF_SLOTS). Block (c, slot): node = wl[slot], thread t
// owns hub t; partial over e in [c*512, c*512+512). X chunk staged in LDS,
// S64T reads coalesced (2 KB per e-row), 4 independent fp64 accumulators.
// ---------------------------------------------------------------------------
__global__ __launch_bounds__(256) void refine_partial_kernel(
    const float* __restrict__ X, const double* __restrict__ S64T,
    const int* __restrict__ cnt, const int* __restrict__ wl,
    double* __restrict__ partials)
{
    const int slot = blockIdx.y;
    const int n = min(min(*cnt, WL_CAP), REF_SLOTS);
    if (slot >= n) return;

    const int t  = threadIdx.x;
    const int c  = blockIdx.x;      // e-chunk 0..7
    const int e0 = c * 512;
    const int node = wl[slot];

    __shared__ float Xs[512];
    if (t < 128)
        *(float4*)&Xs[t * 4] = *(const float4*)&X[(size_t)node * E + e0 + t * 4];
    __syncthreads();

    double a0 = 0, a1 = 0, a2 = 0, a3 = 0;
    for (int e = 0; e < 512; e += 4) {
        const size_t base = (size_t)(e0 + e) * HH + t;
        a0 = fma((double)Xs[e + 0], S64T[base + 0 * HH], a0);
        a1 = fma((double)Xs[e + 1], S64T[base + 1 * HH], a1);
        a2 = fma((double)Xs[e + 2], S64T[base + 2 * HH], a2);
        a3 = fma((double)Xs[e + 3], S64T[base + 3 * HH], a3);
    }
    partials[((size_t)slot * 8 + c) * HH + t] = (a0 + a1) + (a2 + a3);
}

// ---------------------------------------------------------------------------
// Kernel 4b: refine stage B — combine 8 chunk-partials + c64, block argmax
// (first-max, tie -> lower hub position, matching np.argmax). grid REF_SLOTS.
// ---------------------------------------------------------------------------
__global__ __launch_bounds__(256) void refine_reduce_kernel(
    const double* __restrict__ partials, const double* __restrict__ c64,
    const int* __restrict__ hub, const int* __restrict__ cnt,
    const int* __restrict__ wl, int* __restrict__ out)
{
    const int slot = blockIdx.x;
    const int n = min(min(*cnt, WL_CAP), REF_SLOTS);
    if (slot >= n) return;

    const int t = threadIdx.x;
    double v = c64[t];
#pragma unroll
    for (int c = 0; c < 8; ++c)
        v += partials[((size_t)slot * 8 + c) * HH + t];

    __shared__ double rv[256];
    __shared__ int    ri[256];
    rv[t] = v; ri[t] = t;
    __syncthreads();
    for (int s = 128; s; s >>= 1) {
        if (t < s) {
            const bool better = rv[t + s] > rv[t] ||
                                (rv[t + s] == rv[t] && ri[t + s] < ri[t]);
            if (better) { rv[t] = rv[t + s]; ri[t] = ri[t + s]; }
        }
        __syncthreads();
    }
    if (t == 0) out[wl[slot]] = hub[ri[0]];
}

// ---------------------------------------------------------------------------
// Kernel 5: hub nodes map to themselves (isin override). Must run LAST.
// ---------------------------------------------------------------------------
__global__ void hub_override_kernel(const int* __restrict__ hub,
                                    int* __restrict__ out)
{
    const int t = threadIdx.x;
    if (t < HH) { const int h = hub[t]; out[h] = h; }
}

extern "C" void kernel_launch(void* const* d_in, const int* in_sizes, int n_in,
                              void* d_out, int out_size, void* d_ws, size_t ws_size,
                              hipStream_t stream) {
    const float* X   = (const float*)d_in[0];   // [NN, E]
    const int*   hub = (const int*)  d_in[1];   // [HH]
    const float* Wq  = (const float*)d_in[2];   // [E, E]
    const float* bq  = (const float*)d_in[3];   // [E]
    const float* Wk  = (const float*)d_in[4];   // [E, E]
    const float* bk  = (const float*)d_in[5];   // [E]
    int* out = (int*)d_out;                     // [NN]

    // workspace layout (~20.5 MB). partials ALIASES K64 (K64 is dead after
    // cvec64; partials are written only in refine stage A, which runs later
    // in stream order).
    double* K64  = (double*)d_ws;                       // [HH][E]   8 MB
    double* S64T = K64 + (size_t)HH * E;                // [E][HH]   8 MB
    double* c64  = S64T + (size_t)E * HH;               // [HH]      2 KB
    float*  S32  = (float*)(c64 + HH);                  // [HH][E]   4 MB
    float*  c32  = S32 + (size_t)HH * E;                // [HH]      1 KB
    int*    cnt  = (int*)(c32 + HH);                    // [1]
    int*    wl   = cnt + 1;                             // [WL_CAP]  8 KB
    double* partials = K64;                             // [REF_SLOTS][8][HH] 8 MB (alias)

    init_kernel<<<dim3(1), 64, 0, stream>>>(cnt);
    k_proj64_kernel<<<dim3(E / 64, HH / 64), 256, 0, stream>>>(X, hub, Wk, bk, K64);
    s_proj64_kernel<<<dim3(E / 64, HH / 64), 256, 0, stream>>>(K64, Wq, S64T, S32);
    cvec64_kernel<<<dim3(HH), 256, 0, stream>>>(bq, K64, c64, c32);
    scores_argmax_kernel<<<dim3(NN / 32), 256, 0, stream>>>(X, S32, c32, hub, out, cnt, wl);
    refine_partial_kernel<<<dim3(8, REF_SLOTS), 256, 0, stream>>>(X, S64T, cnt, wl, partials);
    refine_reduce_kernel<<<dim3(REF_SLOTS), 256, 0, stream>>>(partials, c64, hub, cnt, wl, out);
    hub_override_kernel<<<dim3(1), 256, 0, stream>>>(hub, out);
}